// Round 1
// 114.225 us; speedup vs baseline: 1.0049x; 1.0049x over previous
//
#include <hip/hip_runtime.h>
#include <stdint.h>

// out[b,i,j] = conv3x3_valid(inp, c*k)[b,i,j]
// c = vt(I=1) from the LIF scan (linear in I; spike/clamp provably inactive
// since I < 9 < 14 for all 1000 steps). c folded into the taps.
//
// R5: persistent double-buffered blocks (T3/T4 counted-vmcnt pattern).
// Previous version: single-shot blocks, __syncthreads() == s_waitcnt vmcnt(0)
// drain -> every wave waits on the block's slowest of 1280 staged loads, and
// HBM reads idle during each block's compute phase. Now: each block owns 4
// strip-jobs; stage job s+1 into buf[p^1] via async global_load_lds while
// computing job s from buf[p]; counted "s_waitcnt vmcnt(5)" + raw s_barrier
// (NOT __syncthreads) keeps the next stage's 5 loads in flight across the
// barrier. LDS pad removed (clamped halo b64 read) -> 2*20480B = 40960B
// exactly -> 4 blocks/CU, grid 1024 = full residency at t=0, zero tail.

#define STRIP  8
#define TROWS  (STRIP + 2)        // 10 input rows per strip
#define TILE_F (TROWS * 512)      // 5120 floats = 20480 B, NO pad
#define GRID_X 1024               // 4 jobs/block, 4 blocks/CU resident

__device__ static inline void async_copy16(const float* gsrc, float* ldst) {
    __builtin_amdgcn_global_load_lds(
        (const __attribute__((address_space(1))) void*)gsrc,
        (__attribute__((address_space(3))) void*)ldst, 16, 0, 0);
}

__global__ __launch_bounds__(256) void snn_conv_db_kernel(
    const float* __restrict__ inp, const float* __restrict__ kw,
    float* __restrict__ out, float c)
{
    __shared__ float tile[2][TILE_F];

    const int tid = threadIdx.x;
    const int tp  = tid & 127;     // column group: output cols 4tp..4tp+3
    const int ty  = tid >> 7;      // row group 0/1 (wave-uniform)
    const int j   = tp << 2;
    const int r0  = ty << 2;       // strip-relative first out row

    // taps (uniform -> scalar loads), c folded; overlaps first staging
    const float k00 = kw[0]*c, k01 = kw[1]*c, k02 = kw[2]*c;
    const float k10 = kw[3]*c, k11 = kw[4]*c, k12 = kw[5]*c;
    const float k20 = kw[6]*c, k21 = kw[7]*c, k22 = kw[8]*c;

    // 10 input rows = one contiguous 20480B global span; 5 insts/thread.
    // Clamp keeps the last strip's nonexistent rows 512/513 inside the batch
    // (duplicated tail data, feeds only discarded outputs orow>=510).
    auto stage = [&](float* dst, int jb) {
        const int b_  = jb >> 6;
        const int f0_ = (jb & 63) * (STRIP * 512);
        const float* g_ = inp + (size_t)b_ * 262144;   // 512*512
#pragma unroll
        for (int r_ = 0; r_ < 5; ++r_) {
            int fo_ = (r_ * 256 + tid) * 4;            // float offset in tile
            int gf_ = min(f0_ + fo_, 262140);
            async_copy16(g_ + gf_, dst + fo_);
        }
    };

    int job = blockIdx.x;                 // jobs: bid, bid+1024, +2048, +3072
    stage(tile[0], job);
    asm volatile("" ::: "memory");        // keep buf0/buf1 load queues ordered

    float x0, x1, x2, x3, x4, x5;
    // b64 halo read: only tp==127 @ ir==9 would overrun row 9; clamp inside
    // the buffer (values feed only o[2],o[3] which tp==127 never stores).
#define LOADX(ir)                                                         \
    {   float4 _a = *(const float4*)(&tbuf[(ir) * 512 + j]);              \
        float2 _h = *(const float2*)(&tbuf[min((ir) * 512 + j + 4,        \
                                               TILE_F - 2)]);             \
        x0=_a.x; x1=_a.y; x2=_a.z; x3=_a.w; x4=_h.x; x5=_h.y; }

#pragma unroll
    for (int it = 0; it < 4; ++it) {
        const int p = it & 1;             // fully unrolled -> static index
        if (it < 3) {
            stage(tile[p ^ 1], job + GRID_X);
            // drain previous stage (and older stores); the 5 loads just
            // issued for job+GRID_X stay in flight across the barrier.
            asm volatile("s_waitcnt vmcnt(5)" ::: "memory");
        } else {
            asm volatile("s_waitcnt vmcnt(0)" ::: "memory");
        }
        __builtin_amdgcn_s_barrier();     // raw: no vmcnt(0) drain
        asm volatile("" ::: "memory");

        // ---- compute job from tile[p]: rolling vertical h-sums ----
        const float* tbuf = tile[p];
        const int i0 = (job & 63) * STRIP;
        float* obase = out + (size_t)(job >> 6) * 260100;   // 510*510

        float a2[4], a1[4], o[4];
        LOADX(r0);
        a2[0] = k00*x0 + k01*x1 + k02*x2;
        a2[1] = k00*x1 + k01*x2 + k02*x3;
        a2[2] = k00*x2 + k01*x3 + k02*x4;
        a2[3] = k00*x3 + k01*x4 + k02*x5;
        LOADX(r0 + 1);
        a1[0] = k00*x0 + k01*x1 + k02*x2;  a2[0] += k10*x0 + k11*x1 + k12*x2;
        a1[1] = k00*x1 + k01*x2 + k02*x3;  a2[1] += k10*x1 + k11*x2 + k12*x3;
        a1[2] = k00*x2 + k01*x3 + k02*x4;  a2[2] += k10*x2 + k11*x3 + k12*x4;
        a1[3] = k00*x3 + k01*x4 + k02*x5;  a2[3] += k10*x3 + k11*x4 + k12*x5;

#pragma unroll
        for (int r = 0; r < 4; ++r) {
            LOADX(r0 + r + 2);
            o[0] = a2[0] + k20*x0 + k21*x1 + k22*x2;
            o[1] = a2[1] + k20*x1 + k21*x2 + k22*x3;
            o[2] = a2[2] + k20*x2 + k21*x3 + k22*x4;
            o[3] = a2[3] + k20*x3 + k21*x4 + k22*x5;

            const int orow = i0 + r0 + r;        // parity(orow) == parity(r)
            if (orow < 510) {
                float* q = obase + (size_t)orow * 510 + j;
                if ((r & 1) == 0) {              // byte offset % 16 == 0
                    if (tp < 127) *(float4*)q = make_float4(o[0],o[1],o[2],o[3]);
                    else          *(float2*)q = make_float2(o[0],o[1]);
                } else {                         // byte offset % 16 == 8
                    *(float2*)q = make_float2(o[0], o[1]);
                    if (tp < 127) *(float2*)(q + 2) = make_float2(o[2], o[3]);
                }
            }
            a2[0] = a1[0] + k10*x0 + k11*x1 + k12*x2;
            a2[1] = a1[1] + k10*x1 + k11*x2 + k12*x3;
            a2[2] = a1[2] + k10*x2 + k11*x3 + k12*x4;
            a2[3] = a1[3] + k10*x3 + k11*x4 + k12*x5;
            a1[0] = k00*x0 + k01*x1 + k02*x2;
            a1[1] = k00*x1 + k01*x2 + k02*x3;
            a1[2] = k00*x2 + k01*x3 + k02*x4;
            a1[3] = k00*x3 + k01*x4 + k02*x5;
        }

        // all waves done READING tile[p^1]'s predecessor... specifically:
        // barrier so no wave's next-iteration stage overwrites tile[p^1]
        // region... (next stage writes tile[p], which this iteration read)
        asm volatile("" ::: "memory");
        __builtin_amdgcn_s_barrier();     // WAR: reads of tile[p] done before
        asm volatile("" ::: "memory");    //      next iter stages into it
        job += GRID_X;
    }
#undef LOADX
}

extern "C" void kernel_launch(void* const* d_in, const int* in_sizes, int n_in,
                              void* d_out, int out_size, void* d_ws, size_t ws_size,
                              hipStream_t stream) {
    (void)in_sizes; (void)n_in; (void)d_ws; (void)ws_size; (void)out_size;
    const float* inp = (const float*)d_in[0];
    const float* kw  = (const float*)d_in[1];
    float* out = (float*)d_out;

    // Closed-form LIF scan with I = 1 (double precision; exact by linearity).
    double v = 0.0;
    v = v + (3000.0 * 1.0 - v) / 30000.0 * 0.01;   // = 0.001
    double vt = v;
    for (int i = 0; i < 999; ++i) {
        v  = v + (3000.0 - v) / 30000.0 * 0.01;
        vt = (v + vt) / 1000.0;
    }
    float c = (float)vt;   // ~0.99983...

    dim3 block(256, 1, 1);
    dim3 grid(GRID_X, 1, 1);   // 1024 blocks x 4 jobs = 4096 strip-jobs
    hipLaunchKernelGGL(snn_conv_db_kernel, grid, block, 0, stream,
                       inp, kw, out, c);
}

// Round 2
// 113.274 us; speedup vs baseline: 1.0133x; 1.0084x over previous
//
#include <hip/hip_runtime.h>
#include <stdint.h>

// out[b,i,j] = conv3x3_valid(inp, c*k)[b,i,j]
// c = vt(I=1) from the LIF scan (linear in I; spike/clamp provably inactive
// since I < 9 < 14 for all 1000 steps). c folded into the taps.
//
// R6: store-drain decoupling. R5's vmcnt(5) sat AFTER compute(s-1)'s global
// stores in the per-wave vmem queue -> waiting to <=5 outstanding drained
// those stores (L2-accept under full-chip write pressure) before every
// compute phase: the hidden serializer that made R5 == R4.
// Fix: make the per-wave vmem count exact & uniform, then count stores into
// the wait so the loop NEVER waits on a store:
//   - strip 63 starts at row 502 (overlaps strip 62 by 2 rows; rows 502/503
//     written twice with bit-identical values) -> all strips have 8 valid
//     output rows -> no row predication, no input clamp.
//   - every row stored as float2 + (tp<127) float2; the tp<127 exec mask is
//     never all-zero in any wave -> exactly 8 store insts/wave/job, always.
//   - per-wave queue at iter-it wait: [stage(s):5][stores(s-1):8][stage(s+1):5]
//     -> it0: vmcnt(5), it1/it2: vmcnt(13), it3: vmcnt(8). Stage(s) drained,
//     stores stay in flight up to 2 jobs deep.

#define STRIP  8
#define TROWS  (STRIP + 2)        // 10 input rows per strip
#define TILE_F (TROWS * 512)      // 5120 floats = 20480 B, NO pad
#define GRID_X 1024               // 4 jobs/block, 4 blocks/CU resident

__device__ static inline void async_copy16(const float* gsrc, float* ldst) {
    __builtin_amdgcn_global_load_lds(
        (const __attribute__((address_space(1))) void*)gsrc,
        (__attribute__((address_space(3))) void*)ldst, 16, 0, 0);
}

__device__ static inline int strip_row0(int s) {    // output/input first row
    return (s == 63) ? 502 : (s << 3);              // strip 63 overlaps by 2
}

__global__ __launch_bounds__(256) void snn_conv_db_kernel(
    const float* __restrict__ inp, const float* __restrict__ kw,
    float* __restrict__ out, float c)
{
    __shared__ float tile[2][TILE_F];

    const int tid = threadIdx.x;
    const int tp  = tid & 127;     // column group: output cols 4tp..4tp+3
    const int ty  = tid >> 7;      // row group 0/1 (wave-uniform)
    const int j   = tp << 2;
    const int r0  = ty << 2;       // strip-relative first out row

    // taps (uniform -> scalar loads via SMEM, lgkmcnt not vmcnt)
    const float k00 = kw[0]*c, k01 = kw[1]*c, k02 = kw[2]*c;
    const float k10 = kw[3]*c, k11 = kw[4]*c, k12 = kw[5]*c;
    const float k20 = kw[6]*c, k21 = kw[7]*c, k22 = kw[8]*c;

    // 10 input rows = one contiguous 20480B global span; exactly 5 vmem
    // insts/thread, no clamp (strip 63 row range 502..511 fits the batch).
    auto stage = [&](float* dst, int jb) {
        const int b_  = jb >> 6;
        const int f0_ = strip_row0(jb & 63) * 512;
        const float* g_ = inp + (size_t)b_ * 262144;   // 512*512
#pragma unroll
        for (int r_ = 0; r_ < 5; ++r_) {
            int fo_ = (r_ * 256 + tid) * 4;            // float offset in tile
            async_copy16(g_ + f0_ + fo_, dst + fo_);
        }
    };

    int job = blockIdx.x;                 // jobs: bid, bid+1024, +2048, +3072
    stage(tile[0], job);
    asm volatile("" ::: "memory");        // keep buf0/buf1 load queues ordered

    float x0, x1, x2, x3, x4, x5;
    // b64 halo read: only tp==127 @ ir==9 would overrun row 9; clamp inside
    // the buffer (values feed only o[2],o[3] which tp==127 never stores).
#define LOADX(ir)                                                         \
    {   float4 _a = *(const float4*)(&tbuf[(ir) * 512 + j]);              \
        float2 _h = *(const float2*)(&tbuf[min((ir) * 512 + j + 4,        \
                                               TILE_F - 2)]);             \
        x0=_a.x; x1=_a.y; x2=_a.z; x3=_a.w; x4=_h.x; x5=_h.y; }

#pragma unroll
    for (int it = 0; it < 4; ++it) {
        const int p = it & 1;             // fully unrolled -> static index
        if (it < 3) {
            stage(tile[p ^ 1], job + GRID_X);
        }
        // Exact counted waits: drain stage(s) (oldest), keep stores(s-1)[8]
        // and stage(s+1)[5] in flight. Never wait on a store in the loop.
        if (it == 0) {
            asm volatile("s_waitcnt vmcnt(5)" ::: "memory");
        } else if (it < 3) {
            asm volatile("s_waitcnt vmcnt(13)" ::: "memory");
        } else {
            asm volatile("s_waitcnt vmcnt(8)" ::: "memory");
        }
        __builtin_amdgcn_s_barrier();     // raw: no vmcnt(0) drain
        asm volatile("" ::: "memory");

        // ---- compute job from tile[p]: rolling vertical h-sums ----
        const float* tbuf = tile[p];
        const int i0 = strip_row0(job & 63);
        float* obase = out + (size_t)(job >> 6) * 260100;   // 510*510

        float a2[4], a1[4], o[4];
        LOADX(r0);
        a2[0] = k00*x0 + k01*x1 + k02*x2;
        a2[1] = k00*x1 + k01*x2 + k02*x3;
        a2[2] = k00*x2 + k01*x3 + k02*x4;
        a2[3] = k00*x3 + k01*x4 + k02*x5;
        LOADX(r0 + 1);
        // same expression shape as the loop body (bit-identical overlap rows)
        a1[0] = k00*x0 + k01*x1 + k02*x2;  a2[0] = a2[0] + k10*x0 + k11*x1 + k12*x2;
        a1[1] = k00*x1 + k01*x2 + k02*x3;  a2[1] = a2[1] + k10*x1 + k11*x2 + k12*x3;
        a1[2] = k00*x2 + k01*x3 + k02*x4;  a2[2] = a2[2] + k10*x2 + k11*x3 + k12*x4;
        a1[3] = k00*x3 + k01*x4 + k02*x5;  a2[3] = a2[3] + k10*x3 + k11*x4 + k12*x5;

#pragma unroll
        for (int r = 0; r < 4; ++r) {
            LOADX(r0 + r + 2);
            o[0] = a2[0] + k20*x0 + k21*x1 + k22*x2;
            o[1] = a2[1] + k20*x1 + k21*x2 + k22*x3;
            o[2] = a2[2] + k20*x2 + k21*x3 + k22*x4;
            o[3] = a2[3] + k20*x3 + k21*x4 + k22*x5;

            const int orow = i0 + r0 + r;            // always < 510 now
            float* q = obase + (size_t)orow * 510 + j;
            // Uniform store count: 2 x float2 per row in EVERY wave (the
            // tp<127 mask is never all-zero -> inst always issues). 8B aligned.
            *(float2*)q = make_float2(o[0], o[1]);
            if (tp < 127) *(float2*)(q + 2) = make_float2(o[2], o[3]);

            a2[0] = a1[0] + k10*x0 + k11*x1 + k12*x2;
            a2[1] = a1[1] + k10*x1 + k11*x2 + k12*x3;
            a2[2] = a1[2] + k10*x2 + k11*x3 + k12*x4;
            a2[3] = a1[3] + k10*x3 + k11*x4 + k12*x5;
            a1[0] = k00*x0 + k01*x1 + k02*x2;
            a1[1] = k00*x1 + k01*x2 + k02*x3;
            a1[2] = k00*x2 + k01*x3 + k02*x4;
            a1[3] = k00*x3 + k01*x4 + k02*x5;
        }

        asm volatile("" ::: "memory");
        __builtin_amdgcn_s_barrier();     // WAR: reads of tile[p] done before
        asm volatile("" ::: "memory");    //      next iter stages into it
        job += GRID_X;
    }
#undef LOADX
}

extern "C" void kernel_launch(void* const* d_in, const int* in_sizes, int n_in,
                              void* d_out, int out_size, void* d_ws, size_t ws_size,
                              hipStream_t stream) {
    (void)in_sizes; (void)n_in; (void)d_ws; (void)ws_size; (void)out_size;
    const float* inp = (const float*)d_in[0];
    const float* kw  = (const float*)d_in[1];
    float* out = (float*)d_out;

    // Closed-form LIF scan with I = 1 (double precision; exact by linearity).
    double v = 0.0;
    v = v + (3000.0 * 1.0 - v) / 30000.0 * 0.01;   // = 0.001
    double vt = v;
    for (int i = 0; i < 999; ++i) {
        v  = v + (3000.0 - v) / 30000.0 * 0.01;
        vt = (v + vt) / 1000.0;
    }
    float c = (float)vt;   // ~0.99983...

    dim3 block(256, 1, 1);
    dim3 grid(GRID_X, 1, 1);   // 1024 blocks x 4 jobs = 4096 strip-jobs
    hipLaunchKernelGGL(snn_conv_db_kernel, grid, block, 0, stream,
                       inp, kw, out, c);
}